// Round 1
// baseline (226.407 us; speedup 1.0000x reference)
//
#include <hip/hip_runtime.h>

// LIF neuron scan over STEP=4 timesteps.
// x: [4, 64, 128, 32, 32] fp32; out same shape.
// Per element: mem = mem*0.25 + x_t; spike = mem > 0.5; mem *= (1-spike).
// Forward value of the surrogate-gradient activation is just the hard
// threshold (stop_gradient(out_s - out_bp) + out_bp == out_s forward).
// Memory-bound: 268 MB total traffic -> ~43 us floor at 6.3 TB/s.

#define DECAY 0.25f

__global__ __launch_bounds__(256) void lif_kernel(const float4* __restrict__ x,
                                                  float4* __restrict__ out,
                                                  int n4) {
    int i = blockIdx.x * blockDim.x + threadIdx.x;
    if (i >= n4) return;

    float4 mem = make_float4(0.f, 0.f, 0.f, 0.f);

#pragma unroll
    for (int t = 0; t < 4; ++t) {
        float4 xv = x[(size_t)t * n4 + i];

        // leaky integrate (mem*0.25 is exact; rounding matches mul+add)
        mem.x = mem.x * DECAY + xv.x;
        mem.y = mem.y * DECAY + xv.y;
        mem.z = mem.z * DECAY + xv.z;
        mem.w = mem.w * DECAY + xv.w;

        // fire (V_TH = 1.0, so v == mem)
        float4 s;
        s.x = mem.x > 0.5f ? 1.f : 0.f;
        s.y = mem.y > 0.5f ? 1.f : 0.f;
        s.z = mem.z > 0.5f ? 1.f : 0.f;
        s.w = mem.w > 0.5f ? 1.f : 0.f;

        out[(size_t)t * n4 + i] = s;

        // reset where spiked
        mem.x = (s.x != 0.f) ? 0.f : mem.x;
        mem.y = (s.y != 0.f) ? 0.f : mem.y;
        mem.z = (s.z != 0.f) ? 0.f : mem.z;
        mem.w = (s.w != 0.f) ? 0.f : mem.w;
    }
}

extern "C" void kernel_launch(void* const* d_in, const int* in_sizes, int n_in,
                              void* d_out, int out_size, void* d_ws, size_t ws_size,
                              hipStream_t stream) {
    const float* x = (const float*)d_in[0];
    float* out = (float*)d_out;

    int n = in_sizes[0];       // 4 * 64 * 128 * 32 * 32 = 33,554,432
    int n4 = n / 16;           // per-timestep element count / 4 (float4 granules)

    int block = 256;
    int grid = (n4 + block - 1) / block;   // 8192 blocks

    lif_kernel<<<grid, block, 0, stream>>>((const float4*)x, (float4*)out, n4);
}